// Round 10
// baseline (173.015 us; speedup 1.0000x reference)
//
#include <hip/hip_runtime.h>
#include <hip/hip_bf16.h>
#include <stdint.h>

typedef __attribute__((ext_vector_type(8))) short bf16x8;
typedef __attribute__((ext_vector_type(4))) float f32x4;

#define B_ROWS 131072
#define BM 16
#define NT 16
#define GRID 512        // 512 * 16 * 16 = 131072 rows

// LDS map (bytes)
#define XPITCH 1040     // 256 f32 + 16B pad = 65 16B-slots (odd -> even bank spread)
#define XB (16 * XPITCH)        // 16640 per buffer
#define HPITCH 656      // 328 bf16 (320 + 8 pad) = 41 slots (odd)
#define HB (16 * HPITCH)        // 10496 per buffer
#define H_OFF (2 * XB)          // 33280
#define A1_OFF (H_OFF + 2 * HB) // 54272
#define A2_OFF (A1_OFF + 16 * 272)  // 58624  (AP=136 bf16 = 272 B/row)
#define LSUM_OFF (A2_OFF + 16 * 272)// 62976
#define LDS_TOTAL (LSUM_OFF + 128 * 4) // 63488
#define AP 136

// packed weight fragment offsets (uint4 units)
#define W1P_OFF 0
#define W2P_OFF 7168
#define W3P_OFF 9216

typedef const __attribute__((address_space(1))) unsigned int gu32;
typedef __attribute__((address_space(3))) unsigned int lu32;

__device__ inline void gl_lds16(const void* g, void* l) {
  __builtin_amdgcn_global_load_lds((gu32*)g, (lu32*)l, 16, 0, 0);
}

__device__ inline uint16_t f2bf(float x) {
  uint32_t u = __float_as_uint(x);
  u += 0x7fffu + ((u >> 16) & 1u);   // RNE
  return (uint16_t)(u >> 16);
}

__device__ inline float tanh_fast(float x) {
  x = fminf(fmaxf(x, -15.f), 15.f);
  float e = __expf(2.f * x);
  return (e - 1.f) / (e + 1.f);
}

__global__ void prepack_kernel(const float* __restrict__ W1,
                               const float* __restrict__ W2,
                               const float* __restrict__ W3,
                               uint4* __restrict__ wp) {
  int tid = blockIdx.x * 256 + threadIdx.x;
  if (tid >= 13312) return;
  int l = tid & 63, f = tid >> 6;
  const float* W; int N, kt, nt;
  if (f < 112)      { W = W1; N = 128; int ff = f;       nt = ff / 14; kt = ff - nt * 14; }
  else if (f < 144) { W = W2; N = 128; int ff = f - 112; nt = ff >> 2; kt = ff & 3; }
  else              { W = W3; N = 256; int ff = f - 144; nt = ff >> 2; kt = ff & 3; }
  int k0  = kt * 32 + (l >> 4) * 8;
  int col = nt * 16 + (l & 15);
  uint16_t v[8];
#pragma unroll
  for (int j = 0; j < 8; j++) v[j] = f2bf(W[(size_t)(k0 + j) * N + col]);
  uint4 o;
  o.x = (uint32_t)v[0] | ((uint32_t)v[1] << 16);
  o.y = (uint32_t)v[2] | ((uint32_t)v[3] << 16);
  o.z = (uint32_t)v[4] | ((uint32_t)v[5] << 16);
  o.w = (uint32_t)v[6] | ((uint32_t)v[7] << 16);
  wp[tid] = o;
}

// h rows -> bf16 LDS (short-lived regs only; j = float4 chunk index in [0,1280))
__device__ inline void stage_h_chunk(uint8_t* hd, const float* hg, int j) {
  int row = j / 80, c4 = j - row * 80;
  float4 v = *(const float4*)(hg + 4 * j);
  uint2 p;
  p.x = (uint32_t)f2bf(v.x) | ((uint32_t)f2bf(v.y) << 16);
  p.y = (uint32_t)f2bf(v.z) | ((uint32_t)f2bf(v.w) << 16);
  *(uint2*)(hd + row * HPITCH + c4 * 8) = p;
}

__global__ __launch_bounds__(512, 2) void fused_kernel(
    const float* __restrict__ x, const float* __restrict__ h,
    const float* __restrict__ b1, const float* __restrict__ b2,
    const float* __restrict__ b3, const uint4* __restrict__ wp,
    float* __restrict__ y, float* __restrict__ ldet) {
  extern __shared__ uint8_t smem[];
  uint16_t* a1   = (uint16_t*)(smem + A1_OFF);
  uint16_t* a2   = (uint16_t*)(smem + A2_OFF);
  float*    lsum = (float*)(smem + LSUM_OFF);

  const int t = threadIdx.x;
  const int wid = t >> 6, l = t & 63;
  const int lr = l & 15, lq = l >> 4;
  const int tile0 = blockIdx.x * NT;

  // ---- load this wave's weight slices into registers (once per block)
  bf16x8 w1[14], w2[4], w3s[4], w3t[4];
#pragma unroll
  for (int kt = 0; kt < 14; kt++)
    w1[kt] = *(const bf16x8*)&wp[W1P_OFF + (wid * 14 + kt) * 64 + l];
#pragma unroll
  for (int kt = 0; kt < 4; kt++) {
    w2[kt]  = *(const bf16x8*)&wp[W2P_OFF + (wid * 4 + kt) * 64 + l];
    w3s[kt] = *(const bf16x8*)&wp[W3P_OFF + (wid * 4 + kt) * 64 + l];
    w3t[kt] = *(const bf16x8*)&wp[W3P_OFF + ((wid + 8) * 4 + kt) * 64 + l];
  }
  const int colc = wid * 16 + lr;      // this lane's output column (0..127)
  const float b1v = b1[colc], b2v = b2[colc];
  const float b3sv = b3[colc], b3tv = b3[128 + colc];

  // ---- prologue: stage tile 0 into buffer 0
  {
    const float* xg = x + (size_t)(tile0 * BM) * 256;
    const float* hg = h + (size_t)(tile0 * BM) * 320;
    // x: one gl_lds per row (1024 B), wave w does rows 2w, 2w+1
#pragma unroll
    for (int k = 0; k < 2; k++) {
      int r = wid * 2 + k;
      gl_lds16(xg + r * 256 + l * 4, smem + r * XPITCH);
    }
    stage_h_chunk(smem + H_OFF, hg, t);
    stage_h_chunk(smem + H_OFF, hg, t + 512);
    if (t < 256) stage_h_chunk(smem + H_OFF, hg, t + 1024);
  }

  int cur = 0;
  for (int it = 0; it < NT; ++it) {
    const int m0 = (tile0 + it) * BM;
    const bool pf = (it + 1 < NT);
    __syncthreads();   // TOP: buffer cur (x via gl_lds + h via ds_write) ready

    const uint8_t* xsc = smem + cur * XB;
    const uint8_t* hsc = smem + H_OFF + cur * HB;

    // ---- issue async x stage for tile it+1 (zero registers held)
    if (pf) {
      const float* xg = x + (size_t)(m0 + BM) * 256;
      uint8_t* xd = smem + (cur ^ 1) * XB;
#pragma unroll
      for (int k = 0; k < 2; k++) {
        int r = wid * 2 + k;
        gl_lds16(xg + r * 256 + l * 4, xd + r * XPITCH);
      }
    }

    // ---- GEMM1: a1 = relu(z @ W1 + b1); z = [x_even | h]; W1 in regs
    {
      f32x4 acc = {};
#pragma unroll
      for (int kt = 0; kt < 4; kt++) {          // x-even part, cvt on read
        union { bf16x8 v; __hip_bfloat162 h2[4]; } u;
#pragma unroll
        for (int i = 0; i < 4; i++) {
          float4 q = *(const float4*)(xsc + lr * XPITCH + kt * 256 + lq * 64 + i * 16);
          u.h2[i] = __float22bfloat162_rn(make_float2(q.x, q.z));
        }
        acc = __builtin_amdgcn_mfma_f32_16x16x32_bf16(u.v, w1[kt], acc, 0, 0, 0);
      }
#pragma unroll
      for (int kh = 0; kh < 10; kh++) {         // h part, bf16 direct
        bf16x8 afr = *(const bf16x8*)(hsc + lr * HPITCH + (kh * 32 + lq * 8) * 2);
        acc = __builtin_amdgcn_mfma_f32_16x16x32_bf16(afr, w1[4 + kh], acc, 0, 0, 0);
      }
#pragma unroll
      for (int r = 0; r < 4; r++)
        a1[(lq * 4 + r) * AP + colc] = f2bf(fmaxf(acc[r] + b1v, 0.f));
    }
    __syncthreads();   // B1: a1 visible

    // ---- stage h for tile it+1 into h[cur^1] (short-lived regs; stall covered)
    if (pf) {
      const float* hg = h + (size_t)(m0 + BM) * 320;
      uint8_t* hd = smem + H_OFF + (cur ^ 1) * HB;
      stage_h_chunk(hd, hg, t);
      stage_h_chunk(hd, hg, t + 512);
      if (t < 256) stage_h_chunk(hd, hg, t + 1024);
    }

    // ---- GEMM2: a2 = relu(a1 @ W2 + b2); W2 in regs
    {
      f32x4 acc = {};
#pragma unroll
      for (int kt = 0; kt < 4; kt++) {
        bf16x8 afr = *(const bf16x8*)&a1[lr * AP + kt * 32 + lq * 8];
        acc = __builtin_amdgcn_mfma_f32_16x16x32_bf16(afr, w2[kt], acc, 0, 0, 0);
      }
#pragma unroll
      for (int r = 0; r < 4; r++)
        a2[(lq * 4 + r) * AP + colc] = f2bf(fmaxf(acc[r] + b2v, 0.f));
    }
    __syncthreads();   // B2: a2 visible; h[cur^1] staged

    // ---- GEMM3: s,t columns; W3 in regs
    f32x4 accS = {}, accT = {};
#pragma unroll
    for (int kt = 0; kt < 4; kt++) {
      bf16x8 afr = *(const bf16x8*)&a2[lr * AP + kt * 32 + lq * 8];
      accS = __builtin_amdgcn_mfma_f32_16x16x32_bf16(afr, w3s[kt], accS, 0, 0, 0);
      accT = __builtin_amdgcn_mfma_f32_16x16x32_bf16(afr, w3t[kt], accT, 0, 0, 0);
    }

    // ---- epilogue: x pair from LDS (exact f32), tanh/exp, y write, log_det
    float lp[4];
#pragma unroll
    for (int r = 0; r < 4; r++) {
      int lrow = lq * 4 + r;
      float sv = tanh_fast(accS[r] + b3sv);
      float tv = accT[r] + b3tv;
      lp[r] = sv;
      const float2 xv = *(const float2*)(xsc + lrow * XPITCH + colc * 8);
      float2 o;
      o.x = xv.x;                              // exact pass-through
      o.y = xv.y * __expf(sv) + tv;
      *(float2*)(y + (size_t)(m0 + lrow) * 256 + 2 * colc) = o;
    }

#pragma unroll
    for (int r = 0; r < 4; r++) {
      float v = lp[r];
      v += __shfl_xor(v, 1);
      v += __shfl_xor(v, 2);
      v += __shfl_xor(v, 4);
      v += __shfl_xor(v, 8);
      if (lr == 0) lsum[wid * 16 + lq * 4 + r] = v;
    }
    __syncthreads();   // B3: lsum visible; all x[cur]/a2 reads done
    if (t < BM) {
      float s = 0.f;
#pragma unroll
      for (int w = 0; w < 8; w++) s += lsum[w * 16 + t];
      ldet[m0 + t] = s;
    }
    cur ^= 1;
  }
}

extern "C" void kernel_launch(void* const* d_in, const int* in_sizes, int n_in,
                              void* d_out, int out_size, void* d_ws, size_t ws_size,
                              hipStream_t stream) {
  const float* x  = (const float*)d_in[0];
  const float* h  = (const float*)d_in[1];
  const float* W1 = (const float*)d_in[2];
  const float* b1 = (const float*)d_in[3];
  const float* W2 = (const float*)d_in[4];
  const float* b2 = (const float*)d_in[5];
  const float* W3 = (const float*)d_in[6];
  const float* b3 = (const float*)d_in[7];
  float* y    = (float*)d_out;
  float* ldet = y + (size_t)B_ROWS * 256;
  uint4* wp   = (uint4*)d_ws;

  prepack_kernel<<<52, 256, 0, stream>>>(W1, W2, W3, wp);

  (void)hipFuncSetAttribute((const void*)fused_kernel,
                            hipFuncAttributeMaxDynamicSharedMemorySize, LDS_TOTAL);
  fused_kernel<<<GRID, 512, LDS_TOTAL, stream>>>(x, h, b1, b2, b3, wp, y, ldet);
}